// Round 3
// baseline (1211.978 us; speedup 1.0000x reference)
//
#include <hip/hip_runtime.h>

typedef unsigned long long u64;
typedef unsigned short u16;

#define NN 4096
#define NCH 64          // u64 chunks per bit-row
#define NSUP 6
#define NBLK_B 512      // persistent boruvka blocks (exactly 2 per CU)

// ============================ init ============================
__global__ void k_init(float* out, int out_n, int* comp, int* ncomp, int* mstcnt,
                       unsigned* bar_cnt, unsigned* bar_gen) {
  int t = blockIdx.x * blockDim.x + threadIdx.x;
  int nt = gridDim.x * blockDim.x;
  for (int v = t; v < NN; v += nt) comp[v] = v;
  for (int i = t; i < out_n; i += nt) out[i] = 0.0f;
  if (t == 0) { *ncomp = NN; *mstcnt = 0; *bar_cnt = 0u; *bar_gen = 0u; }
}

// ============ pack A rows into bits + degree (fused, ballot) ============
// one wave per row; iter k: lanes read 256B contiguous, ballot = chunk k.
__global__ __launch_bounds__(256) void k_packdeg(const float* __restrict__ A,
                                                 u64* __restrict__ bits,
                                                 u16* __restrict__ deg) {
  int t = threadIdx.x;
  int w = t >> 6, lane = t & 63;
  int row = blockIdx.x * 4 + w;
  const float* rp = A + (size_t)row * NN;
  u64 my = 0;
  int dsum = 0;
#pragma unroll 8
  for (int k = 0; k < 64; ++k) {
    float v = rp[k * 64 + lane];
    u64 m = __ballot(v > 0.0f);
    dsum += __popcll(m);
    if (lane == k) my = m;
  }
  bits[(size_t)row * NCH + lane] = my;
  if (lane == 0) deg[row] = (u16)dsum;
}

// ========== inter[i][j] = |N(i) & N(j)| via popcount GEMM ==========
// exact upper-triangular grid (2080 blocks); 2-stage K-split (32KiB LDS);
// swizzle sw(row)=(row^(row>>2))&7: writes at 8-lane/group floor, reads free.
__global__ __launch_bounds__(256) void k_inter(const u64* __restrict__ bits,
                                               u16* __restrict__ inter) {
  __shared__ ulonglong2 L[2][64 * 16];   // 32 KiB total
  int b = blockIdx.x;
  // decode b -> (by, bx), by<=bx ; cum(by) = 64*by - by*(by-1)/2
  int by = (int)((129.0f - sqrtf(16641.0f - 8.0f * (float)b)) * 0.5f) - 1;
  if (by < 0) by = 0;
#define CUM(y) (64 * (y) - ((y) * ((y) - 1)) / 2)
  while (CUM(by + 1) <= b) ++by;
  while (CUM(by) > b) --by;
  int bx = by + (b - CUM(by));
#undef CUM
  int i0 = by * 64, j0 = bx * 64;
  int t = threadIdx.x;
  int tx = t & 15, ty = t >> 4;
  int rowA[4], swA[4], rowB[4], swB[4];
#pragma unroll
  for (int a = 0; a < 4; ++a) {
    rowA[a] = ty * 4 + a; swA[a] = (rowA[a] ^ (rowA[a] >> 2)) & 7;
    rowB[a] = tx * 4 + a; swB[a] = (rowB[a] ^ (rowB[a] >> 2)) & 7;
  }
  int cuL = t & 15, rg = t >> 4;         // staging: thread owns chunk-col cuL, rows rg*4..+3
  int acc[4][4] = {};
  for (int st = 0; st < 2; ++st) {
    __syncthreads();
#pragma unroll
    for (int rr = 0; rr < 4; ++rr) {
      int row = rg * 4 + rr;
      int sw = (row ^ (row >> 2)) & 7;
      L[0][row * 16 + (cuL ^ sw)] =
          reinterpret_cast<const ulonglong2*>(bits + (size_t)(i0 + row) * NCH)[st * 16 + cuL];
      L[1][row * 16 + (cuL ^ sw)] =
          reinterpret_cast<const ulonglong2*>(bits + (size_t)(j0 + row) * NCH)[st * 16 + cuL];
    }
    __syncthreads();
    for (int cu = 0; cu < 16; ++cu) {
      ulonglong2 av[4], bv[4];
#pragma unroll
      for (int a = 0; a < 4; ++a) av[a] = L[0][rowA[a] * 16 + (cu ^ swA[a])];
#pragma unroll
      for (int b2 = 0; b2 < 4; ++b2) bv[b2] = L[1][rowB[b2] * 16 + (cu ^ swB[b2])];
#pragma unroll
      for (int a = 0; a < 4; ++a)
#pragma unroll
        for (int b2 = 0; b2 < 4; ++b2)
          acc[a][b2] += __popcll(av[a].x & bv[b2].x) + __popcll(av[a].y & bv[b2].y);
    }
  }
#pragma unroll
  for (int a = 0; a < 4; ++a) {          // direct tile [i][j]
    int i = i0 + ty * 4 + a;
    ushort4 wv;
    wv.x = (u16)acc[a][0]; wv.y = (u16)acc[a][1];
    wv.z = (u16)acc[a][2]; wv.w = (u16)acc[a][3];
    *reinterpret_cast<ushort4*>(inter + (size_t)i * NN + j0 + tx * 4) = wv;
  }
  if (bx != by) {
#pragma unroll
    for (int b2 = 0; b2 < 4; ++b2) {     // mirror tile [j][i]
      int j = j0 + tx * 4 + b2;
      ushort4 wv;
      wv.x = (u16)acc[0][b2]; wv.y = (u16)acc[1][b2];
      wv.z = (u16)acc[2][b2]; wv.w = (u16)acc[3][b2];
      *reinterpret_cast<ushort4*>(inter + (size_t)j * NN + i0 + ty * 4) = wv;
    }
  }
}

// ================= global barrier (leader-based, device scope) =================
__device__ __forceinline__ void gbar(unsigned* cnt, unsigned* gen, unsigned& mygen) {
  __syncthreads();                        // drains the block's vmcnt (compiler-emitted)
  ++mygen;
  if (threadIdx.x == 0) {
    __threadfence();                      // agent-scope release (L2 writeback)
    unsigned a = __hip_atomic_fetch_add(cnt, 1u, __ATOMIC_ACQ_REL, __HIP_MEMORY_SCOPE_AGENT);
    if (a == (unsigned)(NBLK_B - 1)) {
      __hip_atomic_store(cnt, 0u, __ATOMIC_RELAXED, __HIP_MEMORY_SCOPE_AGENT);
      __hip_atomic_store(gen, mygen, __ATOMIC_RELEASE, __HIP_MEMORY_SCOPE_AGENT);
    } else {
      long long spin = 0;
      while (__hip_atomic_load(gen, __ATOMIC_ACQUIRE, __HIP_MEMORY_SCOPE_AGENT) < mygen) {
        __builtin_amdgcn_s_sleep(8);
        if (++spin > (1ll << 26)) break;  // safety: degrade, never hang
      }
    }
  }
  __syncthreads();
}

// ===== fused Boruvka (all phases) + finalize, persistent 512 blocks =====
__global__ __launch_bounds__(256, 2) void k_boruvka(
    const u16* __restrict__ inter, const u16* __restrict__ deg, int* comp,
    u64* nkey, int* nu, int* ncomp_g, int* mstcnt,
    u64* mkey, int* mi, int* mj,
    unsigned* bar_cnt, unsigned* bar_gen,
    int* labels_g, float* invs_g, float* out) {
  __shared__ u16 comp_s[NN];     // 8 KiB  (finalize: root->rank LUT)
  __shared__ u16 deg_s[NN];      // 8 KiB  (merge: scratch mark array)
  __shared__ int parent_s[NN];   // 16 KiB (finalize: p[])
  __shared__ u64 cbest_s[NN];    // 32 KiB
  __shared__ u64 rk_s[256];      // 2 KiB
  __shared__ int rs_s[256];      // 1 KiB
  __shared__ int roots[16];
  __shared__ int rcnt, cnt_s, chg_s, changed;
  __shared__ int szs[8];
  __shared__ float ivs[8];
  int t = threadIdx.x;
  unsigned mygen = 0;
  for (int ph = 0; ph < 12; ++ph) {
    // ---- stage comp/deg into LDS ----
    for (int i = t; i < NN; i += 256) { comp_s[i] = (u16)comp[i]; deg_s[i] = deg[i]; }
    __syncthreads();
    // ---- scan: 8 rows per block, 2 rows per wave ----
    int w = t >> 6, lane = t & 63;
    for (int rr = 0; rr < 2; ++rr) {
      int v = blockIdx.x * 8 + w * 2 + rr;
      int cv = (int)comp_s[v];
      int dv = (int)deg_s[v];
      const u16* row = inter + (size_t)v * NN;
      unsigned bs = 0; int bu = -1;
      for (int it = 0; it < 8; ++it) {
        int ub = it * 512 + lane * 8;
        uint4 pv = *reinterpret_cast<const uint4*>(row + ub);
        uint4 dg = *reinterpret_cast<const uint4*>(deg_s + ub);
        uint4 cs = *reinterpret_cast<const uint4*>(comp_s + ub);
        unsigned pw[4] = { pv.x, pv.y, pv.z, pv.w };
        unsigned dw[4] = { dg.x, dg.y, dg.z, dg.w };
        unsigned cw[4] = { cs.x, cs.y, cs.z, cs.w };
#pragma unroll
        for (int h = 0; h < 4; ++h) {
#pragma unroll
          for (int lo = 0; lo < 2; ++lo) {
            int iv = (int)((pw[h] >> (lo * 16)) & 0xFFFF);
            int du = (int)((dw[h] >> (lo * 16)) & 0xFFFF);
            int cu = (int)((cw[h] >> (lo * 16)) & 0xFFFF);
            int un = dv + du - iv;
            float s = (un > 0) ? ((float)iv / (float)un) : 0.0f;  // exact fp32 div == numpy
            unsigned sb = __float_as_uint(s);
            if (cu != cv && (bu < 0 || sb > bs)) { bs = sb; bu = ub + h * 2 + lo; }
          }
        }
      }
      u64 key = (bu >= 0) ? (((u64)bs << 32) | (u64)(0xFFFFFFFFu - (unsigned)bu)) : 0ull;
#pragma unroll
      for (int off = 32; off > 0; off >>= 1) {    // wave max-reduce
        unsigned lo = (unsigned)key, hi = (unsigned)(key >> 32);
        unsigned olo = __shfl_xor(lo, off, 64), ohi = __shfl_xor(hi, off, 64);
        u64 o = ((u64)ohi << 32) | (u64)olo;
        if (o > key) key = o;
      }
      if (lane == 0) {
        u64 pk = 0; int u = -1;
        if (key != 0ull) {
          unsigned simb = (unsigned)(key >> 32);
          u = (int)(0xFFFFFFFFu - (unsigned)(key & 0xFFFFFFFFull));
          int i = v < u ? v : u, j = v < u ? u : v;
          unsigned idx = (unsigned)i * (unsigned)(2 * NN - i - 1) / 2u + (unsigned)(j - i - 1);
          pk = ((u64)simb << 24) | (u64)(0xFFFFFFu - idx);        // global pair key
        }
        nkey[v] = pk; nu[v] = u;
      }
    }
    gbar(bar_cnt, bar_gen, mygen);
    // ---- merge on block 0 ----
    if (blockIdx.x == 0) {
      for (int c = t; c < NN; c += 256) { parent_s[c] = c; cbest_s[c] = 0ull; }
      __syncthreads();
      for (int v = t; v < NN; v += 256) {
        u64 k = nkey[v];
        if (k) atomicMax(&cbest_s[(int)comp_s[v]], k);
      }
      __syncthreads();
      for (int v = t; v < NN; v += 256) {
        u64 k = nkey[v];
        if (!k) continue;
        int c = (int)comp_s[v];
        if (k == cbest_s[c]) {
          int u = nu[v];
          int cu = (int)comp_s[u];
          bool mutual = (cbest_s[cu] == k);
          if (!mutual || v < u) {
            int slot = atomicAdd(mstcnt, 1);
            mkey[slot] = k; mi[slot] = v; mj[slot] = u;
          }
          parent_s[c] = cu;               // unique writer per component (keys unique)
        }
      }
      __syncthreads();
      for (int c = t; c < NN; c += 256) { // break mutual 2-cycles: keep smaller root
        int pc = parent_s[c];
        if (parent_s[pc] == c && c < pc) parent_s[c] = c;
      }
      __syncthreads();
      for (int it = 0; it < 13; ++it) {   // pointer jumping w/ convergence check
        if (t == 0) chg_s = 0;
        __syncthreads();
        for (int c = t; c < NN; c += 256) {
          int p1 = parent_s[c], p2 = parent_s[p1];
          if (p1 != p2) { parent_s[c] = p2; chg_s = 1; }
        }
        __syncthreads();
        if (!chg_s) break;
      }
      for (int c = t; c < NN; c += 256) deg_s[c] = 0;   // deg_s as mark scratch
      if (t == 0) cnt_s = 0;
      __syncthreads();
      for (int v = t; v < NN; v += 256) {
        int nc = parent_s[(int)comp_s[v]];
        comp[v] = nc;                     // write back to global
        deg_s[nc] = 1;
      }
      __syncthreads();
      int lc = 0;
      for (int c = t; c < NN; c += 256) lc += (int)deg_s[c];
      atomicAdd(&cnt_s, lc);
      __syncthreads();
      if (t == 0) *ncomp_g = cnt_s;
    }
    gbar(bar_cnt, bar_gen, mygen);
    int nc = __hip_atomic_load(ncomp_g, __ATOMIC_ACQUIRE, __HIP_MEMORY_SCOPE_AGENT);
    if (nc <= 1) break;
  }
  if (blockIdx.x != 0) return;
  // ======== finalize on block 0 (256 threads) ========
  int nm = *mstcnt;                       // 4095
  for (int v = t; v < NN; v += 256) parent_s[v] = v;      // parent_s := p[]
  // remove the 5 smallest MST edges (lowest sim / largest pair-idx first)
  for (int pass = 0; pass < NSUP - 1; ++pass) {
    u64 bk = ~0ull; int bsel = -1;
    for (int e = t; e < nm; e += 256) { u64 k = mkey[e]; if (k < bk) { bk = k; bsel = e; } }
    rk_s[t] = bk; rs_s[t] = bsel;
    __syncthreads();
    for (int s = 128; s > 0; s >>= 1) {
      if (t < s && rk_s[t + s] < rk_s[t]) { rk_s[t] = rk_s[t + s]; rs_s[t] = rs_s[t + s]; }
      __syncthreads();
    }
    if (t == 0) mkey[rs_s[0]] = ~0ull;    // mark removed
    __syncthreads();
  }
  // connected components over kept edges (min-label hook + jump)
  for (int round = 0; round < 64; ++round) {
    if (t == 0) changed = 0;
    __syncthreads();
    for (int e = t; e < nm; e += 256) {
      if (mkey[e] == ~0ull) continue;
      int a = parent_s[mi[e]], b = parent_s[mj[e]];
      if (a == b) continue;
      int m = a < b ? a : b, M = a < b ? b : a;
      int old = atomicMin(&parent_s[M], m);
      if (old > m) changed = 1;
    }
    __syncthreads();
    for (int rep = 0; rep < 3; ++rep) {
      for (int v = t; v < NN; v += 256) parent_s[v] = parent_s[parent_s[v]];
      __syncthreads();
    }
    int ch = changed;
    __syncthreads();
    if (!ch) break;
  }
  for (int rep = 0; rep < 13; ++rep) {    // full compression -> p[v] = component min index
    for (int v = t; v < NN; v += 256) parent_s[v] = parent_s[parent_s[v]];
    __syncthreads();
  }
  if (t == 0) rcnt = 0;
  __syncthreads();
  for (int v = t; v < NN; v += 256)
    if (parent_s[v] == v) { int s = atomicAdd(&rcnt, 1); if (s < 16) roots[s] = v; }
  __syncthreads();
  if (t == 0) {                           // sort roots asc == first-occurrence label order
    int c = rcnt > 16 ? 16 : rcnt;
    for (int a = 1; a < c; ++a) {
      int x = roots[a]; int b = a - 1;
      while (b >= 0 && roots[b] > x) { roots[b + 1] = roots[b]; --b; }
      roots[b + 1] = x;
    }
  }
  if (t < 8) szs[t] = 0;
  __syncthreads();
  if (t < rcnt && t < 16) comp_s[roots[t]] = (u16)t;      // comp_s := root->rank LUT
  __syncthreads();
  for (int v = t; v < NN; v += 256) {
    int lab = (int)comp_s[parent_s[v]];
    labels_g[v] = lab;
    atomicAdd(&szs[lab], 1);
  }
  __syncthreads();
  if (t < rcnt && t < 8) {
    float iv = 1.0f / sqrtf((float)szs[t] + 1e-10f);      // bit-matches reference P
    ivs[t] = iv; invs_g[t] = iv;
  }
  __syncthreads();
  for (int v = t; v < NN; v += 256) {     // P at out+1572, row-major [4096][6]
    int lab = (int)comp_s[parent_s[v]];
    float* base = out + 1572 + v * 6;
#pragma unroll
    for (int b = 0; b < 6; ++b) base[b] = (b == lab) ? ivs[lab] : 0.0f;
  }
}

// ===== X_coarse = P^T X : label-indexed column sums =====
__global__ __launch_bounds__(256) void k_xcoarse(const float* __restrict__ X,
                                                 const int* __restrict__ labels,
                                                 const float* __restrict__ invs, float* out) {
  __shared__ float acc[6][256];
  __shared__ int labs[64];
  __shared__ float ivl[64];
  int t = threadIdx.x;
#pragma unroll
  for (int m = 0; m < 6; ++m) acc[m][t] = 0.0f;
  if (t < 64) { int v = blockIdx.x * 64 + t; int l = labels[v]; labs[t] = l; ivl[t] = invs[l]; }
  __syncthreads();
  int v0 = blockIdx.x * 64;
  for (int r = 0; r < 64; ++r) {
    float x = X[(size_t)(v0 + r) * 256 + t];
    acc[labs[r]][t] += ivl[r] * x;
  }
  __syncthreads();
#pragma unroll
  for (int m = 0; m < 6; ++m) atomicAdd(&out[m * 256 + t], acc[m][t]);
}

// ===== A_coarse = P^T A P : per-row neighbor-label counts from bit rows =====
__global__ __launch_bounds__(256) void k_acoarse(const u64* __restrict__ bits,
                                                 const int* __restrict__ labels,
                                                 const float* __restrict__ invs, float* out) {
  __shared__ unsigned char labs[NN];   // 4 KiB
  __shared__ float accA[36];
  __shared__ float ivsl[8];
  int t = threadIdx.x;
  for (int v = t; v < NN; v += 256) labs[v] = (unsigned char)labels[v];
  if (t < 36) accA[t] = 0.0f;
  if (t < 6) ivsl[t] = invs[t];
  __syncthreads();
  int i = blockIdx.x * 256 + t;
  u64 cnt = 0;   // six 10-bit counters
  const u64* row = bits + (size_t)i * NCH;
  for (int c = 0; c < NCH; ++c) {
    u64 wm = row[c];
    while (wm) {
      int j = (c << 6) + __builtin_ctzll(wm);
      wm &= wm - 1;
      cnt += 1ull << (labs[j] * 10);
    }
  }
  int li = labs[i];
  float fi = ivsl[li];
#pragma unroll
  for (int b = 0; b < 6; ++b) {
    float cb = (float)((cnt >> (b * 10)) & 1023ull);
    if (cb != 0.0f) atomicAdd(&accA[li * 6 + b], fi * ivsl[b] * cb);
  }
  __syncthreads();
  if (t < 36) atomicAdd(&out[1536 + t], accA[t]);
}

// ============================ launch ============================
extern "C" void kernel_launch(void* const* d_in, const int* in_sizes, int n_in,
                              void* d_out, int out_size, void* d_ws, size_t ws_size,
                              hipStream_t stream) {
  const float* X = (const float*)d_in[0];
  const float* A = (const float*)d_in[1];
  float* out = (float*)d_out;

  char* wp = (char*)d_ws;
  size_t off = 0;
#define WALLOC(ty, name, count) \
  ty* name = (ty*)(wp + off);   \
  off += (((size_t)(count) * sizeof(ty)) + 255) & ~(size_t)255;
  WALLOC(u64, bits, (size_t)NN * NCH)      // 2 MiB
  WALLOC(u16, inter, (size_t)NN * NN)      // 32 MiB
  WALLOC(u16, deg, NN)
  WALLOC(int, comp, NN)
  WALLOC(u64, nkey, NN)
  WALLOC(int, nu, NN)
  WALLOC(u64, mkey, 4352)
  WALLOC(int, mi, 4352)
  WALLOC(int, mj, 4352)
  WALLOC(int, labels, NN)
  WALLOC(float, invs, 8)
  WALLOC(int, ncomp, 1)
  WALLOC(int, mstcnt, 1)
  WALLOC(unsigned, bar_cnt, 1)
  WALLOC(unsigned, bar_gen, 1)
#undef WALLOC
  if (off > ws_size) return;   // workspace too small: leave output zeroed (clean fail)

  k_init<<<64, 256, 0, stream>>>(out, out_size, comp, ncomp, mstcnt, bar_cnt, bar_gen);
  k_packdeg<<<NN / 4, 256, 0, stream>>>(A, bits, deg);
  k_inter<<<2080, 256, 0, stream>>>(bits, inter);
  k_boruvka<<<NBLK_B, 256, 0, stream>>>(inter, deg, comp, nkey, nu, ncomp, mstcnt,
                                        mkey, mi, mj, bar_cnt, bar_gen,
                                        labels, invs, out);
  k_xcoarse<<<64, 256, 0, stream>>>(X, labels, invs, out);
  k_acoarse<<<16, 256, 0, stream>>>(bits, labels, invs, out);
}

// Round 4
// 456.457 us; speedup vs baseline: 2.6552x; 2.6552x over previous
//
#include <hip/hip_runtime.h>

typedef unsigned long long u64;
typedef unsigned short u16;

#define NN 4096
#define NCH 64          // u64 chunks per bit-row
#define NSUP 6

// ============================ init ============================
__global__ void k_init(float* out, int out_n, int* comp, int* ncomp, int* mstcnt) {
  int t = blockIdx.x * blockDim.x + threadIdx.x;
  int nt = gridDim.x * blockDim.x;
  for (int v = t; v < NN; v += nt) comp[v] = v;
  for (int i = t; i < out_n; i += nt) out[i] = 0.0f;
  if (t == 0) { *ncomp = NN; *mstcnt = 0; }
}

// ============ pack A rows into bits + degree (fused, ballot) ============
// one wave per row; iter k: lanes read 256B contiguous, ballot = chunk k.
__global__ __launch_bounds__(256) void k_packdeg(const float* __restrict__ A,
                                                 u64* __restrict__ bits,
                                                 u16* __restrict__ deg) {
  int t = threadIdx.x;
  int w = t >> 6, lane = t & 63;
  int row = blockIdx.x * 4 + w;
  const float* rp = A + (size_t)row * NN;
  u64 my = 0;
  int dsum = 0;
#pragma unroll 8
  for (int k = 0; k < 64; ++k) {
    float v = rp[k * 64 + lane];
    u64 m = __ballot(v > 0.0f);
    dsum += __popcll(m);
    if (lane == k) my = m;
  }
  bits[(size_t)row * NCH + lane] = my;
  if (lane == 0) deg[row] = (u16)dsum;
}

// ========== inter[i][j] = |N(i) & N(j)| via popcount GEMM ==========
// exact upper-triangular grid (2080 blocks); 2-stage K-split (32KiB LDS);
// swizzle sw(row)=(row^(row>>2))&7: staging writes at 8-group floor, reads 2-way.
__global__ __launch_bounds__(256) void k_inter(const u64* __restrict__ bits,
                                               u16* __restrict__ inter) {
  __shared__ ulonglong2 L[2][64 * 16];   // 32 KiB total
  int b = blockIdx.x;
  // decode b -> (by, bx), by<=bx ; cum(by) = 64*by - by*(by-1)/2
  int by = (int)((129.0f - sqrtf(16641.0f - 8.0f * (float)b)) * 0.5f) - 1;
  if (by < 0) by = 0;
#define CUM(y) (64 * (y) - ((y) * ((y) - 1)) / 2)
  while (CUM(by + 1) <= b) ++by;
  while (CUM(by) > b) --by;
  int bx = by + (b - CUM(by));
#undef CUM
  int i0 = by * 64, j0 = bx * 64;
  int t = threadIdx.x;
  int tx = t & 15, ty = t >> 4;
  int rowA[4], swA[4], rowB[4], swB[4];
#pragma unroll
  for (int a = 0; a < 4; ++a) {
    rowA[a] = ty * 4 + a; swA[a] = (rowA[a] ^ (rowA[a] >> 2)) & 7;
    rowB[a] = tx * 4 + a; swB[a] = (rowB[a] ^ (rowB[a] >> 2)) & 7;
  }
  int cuL = t & 15, rg = t >> 4;         // staging: thread owns chunk-col cuL, rows rg*4..+3
  int acc[4][4] = {};
  for (int st = 0; st < 2; ++st) {
    __syncthreads();
#pragma unroll
    for (int rr = 0; rr < 4; ++rr) {
      int row = rg * 4 + rr;
      int sw = (row ^ (row >> 2)) & 7;
      L[0][row * 16 + (cuL ^ sw)] =
          reinterpret_cast<const ulonglong2*>(bits + (size_t)(i0 + row) * NCH)[st * 16 + cuL];
      L[1][row * 16 + (cuL ^ sw)] =
          reinterpret_cast<const ulonglong2*>(bits + (size_t)(j0 + row) * NCH)[st * 16 + cuL];
    }
    __syncthreads();
    for (int cu = 0; cu < 16; ++cu) {
      ulonglong2 av[4], bv[4];
#pragma unroll
      for (int a = 0; a < 4; ++a) av[a] = L[0][rowA[a] * 16 + (cu ^ swA[a])];
#pragma unroll
      for (int b2 = 0; b2 < 4; ++b2) bv[b2] = L[1][rowB[b2] * 16 + (cu ^ swB[b2])];
#pragma unroll
      for (int a = 0; a < 4; ++a)
#pragma unroll
        for (int b2 = 0; b2 < 4; ++b2)
          acc[a][b2] += __popcll(av[a].x & bv[b2].x) + __popcll(av[a].y & bv[b2].y);
    }
  }
#pragma unroll
  for (int a = 0; a < 4; ++a) {          // direct tile [i][j]
    int i = i0 + ty * 4 + a;
    ushort4 wv;
    wv.x = (u16)acc[a][0]; wv.y = (u16)acc[a][1];
    wv.z = (u16)acc[a][2]; wv.w = (u16)acc[a][3];
    *reinterpret_cast<ushort4*>(inter + (size_t)i * NN + j0 + tx * 4) = wv;
  }
  if (bx != by) {
#pragma unroll
    for (int b2 = 0; b2 < 4; ++b2) {     // mirror tile [j][i]
      int j = j0 + tx * 4 + b2;
      ushort4 wv;
      wv.x = (u16)acc[0][b2]; wv.y = (u16)acc[1][b2];
      wv.z = (u16)acc[2][b2]; wv.w = (u16)acc[3][b2];
      *reinterpret_cast<ushort4*>(inter + (size_t)j * NN + i0 + ty * 4) = wv;
    }
  }
}

// ===== Boruvka phase A: per-node best outgoing edge (one WAVE per row) =====
// 16 rows/block to amortize the comp/deg LDS staging.
// node-local order: (sim desc, partner u asc)  ==  (sim desc, pair-index asc)
__global__ __launch_bounds__(256) void k_scan(const u16* __restrict__ inter,
                                              const u16* __restrict__ deg,
                                              const int* __restrict__ comp,
                                              const int* __restrict__ ncomp,
                                              u64* __restrict__ nkey,
                                              int* __restrict__ nu) {
  if (*ncomp <= 1) return;
  __shared__ int comp_s[NN];   // 16 KiB
  __shared__ u16 deg_s[NN];    // 8 KiB
  int t = threadIdx.x;
  for (int i = t; i < NN / 4; i += 256)
    reinterpret_cast<int4*>(comp_s)[i] = reinterpret_cast<const int4*>(comp)[i];
  for (int i = t; i < NN / 8; i += 256)
    reinterpret_cast<uint4*>(deg_s)[i] = reinterpret_cast<const uint4*>(deg)[i];
  __syncthreads();
  int w = t >> 6, lane = t & 63;
  for (int rr = 0; rr < 4; ++rr) {
    int v = blockIdx.x * 16 + w * 4 + rr;
    int cv = comp_s[v];
    int dv = (int)deg_s[v];
    const u16* row = inter + (size_t)v * NN;
    unsigned bs = 0; int bu = -1;
    for (int it = 0; it < 8; ++it) {
      int ub = it * 512 + lane * 8;
      uint4 pv = *reinterpret_cast<const uint4*>(row + ub);          // 8× u16 inter
      uint4 dg = *reinterpret_cast<const uint4*>(deg_s + ub);        // 8× u16 deg
      int4 c0 = reinterpret_cast<const int4*>(comp_s)[ub >> 2];
      int4 c1 = reinterpret_cast<const int4*>(comp_s)[(ub >> 2) + 1];
      int iv_[8] = { (int)(pv.x & 0xFFFF), (int)(pv.x >> 16), (int)(pv.y & 0xFFFF), (int)(pv.y >> 16),
                     (int)(pv.z & 0xFFFF), (int)(pv.z >> 16), (int)(pv.w & 0xFFFF), (int)(pv.w >> 16) };
      int du_[8] = { (int)(dg.x & 0xFFFF), (int)(dg.x >> 16), (int)(dg.y & 0xFFFF), (int)(dg.y >> 16),
                     (int)(dg.z & 0xFFFF), (int)(dg.z >> 16), (int)(dg.w & 0xFFFF), (int)(dg.w >> 16) };
      int cs_[8] = { c0.x, c0.y, c0.z, c0.w, c1.x, c1.y, c1.z, c1.w };
#pragma unroll
      for (int k = 0; k < 8; ++k) {
        int un = dv + du_[k] - iv_[k];
        float s = (un > 0) ? ((float)iv_[k] / (float)un) : 0.0f;     // exact fp32 div == numpy
        unsigned sb = __float_as_uint(s);
        if (cs_[k] != cv && (bu < 0 || sb > bs)) { bs = sb; bu = ub + k; }
      }
    }
    u64 key = (bu >= 0) ? (((u64)bs << 32) | (u64)(0xFFFFFFFFu - (unsigned)bu)) : 0ull;
#pragma unroll
    for (int off = 32; off > 0; off >>= 1) {                          // wave max-reduce
      unsigned lo = (unsigned)key, hi = (unsigned)(key >> 32);
      unsigned olo = __shfl_xor(lo, off, 64), ohi = __shfl_xor(hi, off, 64);
      u64 o = ((u64)ohi << 32) | (u64)olo;
      if (o > key) key = o;
    }
    if (lane == 0) {
      u64 pk = 0; int u = -1;
      if (key != 0ull) {
        unsigned simb = (unsigned)(key >> 32);
        u = (int)(0xFFFFFFFFu - (unsigned)(key & 0xFFFFFFFFull));
        int i = v < u ? v : u, j = v < u ? u : v;
        unsigned idx = (unsigned)i * (unsigned)(2 * NN - i - 1) / 2u + (unsigned)(j - i - 1);
        pk = ((u64)simb << 24) | (u64)(0xFFFFFFu - idx);              // global pair key
      }
      nkey[v] = pk; nu[v] = u;
    }
  }
}

// ===== Boruvka phase B: component-best, hook, 2-cycle break, jump (LDS) =====
__global__ __launch_bounds__(1024) void k_merge(const u64* __restrict__ nkey,
                                                const int* __restrict__ nu,
                                                int* comp, int* ncomp, int* mstcnt,
                                                u64* mkey, int* mi, int* mj) {
  if (*ncomp <= 1) return;
  __shared__ int parent_s[NN];        // 16 KiB
  __shared__ u64 cbest_s[NN];         // 32 KiB
  __shared__ unsigned char mk_s[NN];  // 4 KiB
  __shared__ int cnt_s, chg_s;
  int t = threadIdx.x;
  for (int c = t; c < NN; c += 1024) { parent_s[c] = c; cbest_s[c] = 0ull; }
  __syncthreads();
  for (int v = t; v < NN; v += 1024) {
    u64 k = nkey[v];
    if (k) atomicMax(&cbest_s[comp[v]], k);
  }
  __syncthreads();
  for (int v = t; v < NN; v += 1024) {
    u64 k = nkey[v];
    if (!k) continue;
    int c = comp[v];
    if (k == cbest_s[c]) {
      int u = nu[v];
      int cu = comp[u];
      bool mutual = (cbest_s[cu] == k);
      if (!mutual || v < u) {
        int slot = atomicAdd(mstcnt, 1);
        mkey[slot] = k; mi[slot] = v; mj[slot] = u;
      }
      parent_s[c] = cu;                // one winner per component
    }
  }
  __syncthreads();
  for (int c = t; c < NN; c += 1024) { // break mutual 2-cycles: keep smaller root
    int pc = parent_s[c];
    if (parent_s[pc] == c && c < pc) parent_s[c] = c;
  }
  __syncthreads();
  for (int it = 0; it < 13; ++it) {    // pointer jumping w/ convergence check
    if (t == 0) chg_s = 0;
    __syncthreads();
    for (int c = t; c < NN; c += 1024) {
      int p1 = parent_s[c], p2 = parent_s[p1];
      if (p1 != p2) { parent_s[c] = p2; chg_s = 1; }
    }
    __syncthreads();
    if (!chg_s) break;
  }
  for (int c = t; c < NN; c += 1024) mk_s[c] = 0;
  if (t == 0) cnt_s = 0;
  __syncthreads();
  for (int v = t; v < NN; v += 1024) {
    int nc = parent_s[comp[v]];
    comp[v] = nc;
    mk_s[nc] = 1;
  }
  __syncthreads();
  int lc = 0;
  for (int c = t; c < NN; c += 1024) lc += mk_s[c];
  atomicAdd(&cnt_s, lc);
  __syncthreads();
  if (t == 0) *ncomp = cnt_s;
}

// ===== finalize: drop 5 smallest MST edges, CC, labels, P =====
__global__ __launch_bounds__(1024) void k_finalize(u64* mkey, const int* __restrict__ mi,
                                                   const int* __restrict__ mj,
                                                   const int* __restrict__ mstcnt,
                                                   int* labels_g, float* invs_g, float* out) {
  __shared__ int p[NN];        // 16 KiB
  __shared__ int rr[NN];       // 16 KiB (root -> rank LUT)
  __shared__ u64 rk[1024];
  __shared__ int rs[1024];
  __shared__ int roots[16];
  __shared__ int rcnt;
  __shared__ int szs[8];
  __shared__ float ivs[8];
  __shared__ int changed;
  int t = threadIdx.x;
  int nm = *mstcnt;            // 4095
  for (int v = t; v < NN; v += 1024) p[v] = v;
  // remove the 5 smallest edges (smallest keys == lowest sim / largest pair-idx)
  for (int pass = 0; pass < NSUP - 1; ++pass) {
    u64 bk = ~0ull; int bs = -1;
    for (int e = t; e < nm; e += 1024) { u64 k = mkey[e]; if (k < bk) { bk = k; bs = e; } }
    rk[t] = bk; rs[t] = bs;
    __syncthreads();
    for (int s = 512; s > 0; s >>= 1) {
      if (t < s && rk[t + s] < rk[t]) { rk[t] = rk[t + s]; rs[t] = rs[t + s]; }
      __syncthreads();
    }
    if (t == 0) mkey[rs[0]] = ~0ull;   // mark removed
    __syncthreads();
  }
  // connected components over kept edges (min-label hook + jump)
  for (int round = 0; round < 64; ++round) {
    if (t == 0) changed = 0;
    __syncthreads();
    for (int e = t; e < nm; e += 1024) {
      if (mkey[e] == ~0ull) continue;
      int a = p[mi[e]], b = p[mj[e]];
      if (a == b) continue;
      int m = a < b ? a : b, M = a < b ? b : a;
      int old = atomicMin(&p[M], m);
      if (old > m) changed = 1;
    }
    __syncthreads();
    for (int rep = 0; rep < 3; ++rep) {
      for (int v = t; v < NN; v += 1024) p[v] = p[p[v]];
      __syncthreads();
    }
    int ch = changed;
    __syncthreads();
    if (!ch) break;
  }
  for (int rep = 0; rep < 13; ++rep) {   // full compression -> p[v] = component min index
    for (int v = t; v < NN; v += 1024) p[v] = p[p[v]];
    __syncthreads();
  }
  if (t == 0) rcnt = 0;
  __syncthreads();
  for (int v = t; v < NN; v += 1024)
    if (p[v] == v) { int s = atomicAdd(&rcnt, 1); if (s < 16) roots[s] = v; }
  __syncthreads();
  if (t == 0) {                           // sort roots asc -> first-occurrence label order
    int c = rcnt > 16 ? 16 : rcnt;
    for (int a = 1; a < c; ++a) {
      int x = roots[a]; int b = a - 1;
      while (b >= 0 && roots[b] > x) { roots[b + 1] = roots[b]; --b; }
      roots[b + 1] = x;
    }
  }
  if (t < 8) szs[t] = 0;
  __syncthreads();
  if (t < rcnt && t < 16) rr[roots[t]] = t;
  __syncthreads();
  for (int v = t; v < NN; v += 1024) {
    int lab = rr[p[v]];
    labels_g[v] = lab;
    atomicAdd(&szs[lab], 1);
  }
  __syncthreads();
  if (t < rcnt && t < 8) {
    float iv = 1.0f / sqrtf((float)szs[t] + 1e-10f);   // bit-matches reference P entries
    ivs[t] = iv; invs_g[t] = iv;
  }
  __syncthreads();
  for (int v = t; v < NN; v += 1024) {                 // P at out+1572, row-major [4096][6]
    int lab = rr[p[v]];
    float* base = out + 1572 + v * 6;
#pragma unroll
    for (int b = 0; b < 6; ++b) base[b] = (b == lab) ? ivs[lab] : 0.0f;
  }
}

// ===== X_coarse = P^T X : label-indexed column sums =====
__global__ __launch_bounds__(256) void k_xcoarse(const float* __restrict__ X,
                                                 const int* __restrict__ labels,
                                                 const float* __restrict__ invs, float* out) {
  __shared__ float acc[6][256];
  __shared__ int labs[64];
  __shared__ float ivl[64];
  int t = threadIdx.x;
#pragma unroll
  for (int m = 0; m < 6; ++m) acc[m][t] = 0.0f;
  if (t < 64) { int v = blockIdx.x * 64 + t; int l = labels[v]; labs[t] = l; ivl[t] = invs[l]; }
  __syncthreads();
  int v0 = blockIdx.x * 64;
  for (int r = 0; r < 64; ++r) {
    float x = X[(size_t)(v0 + r) * 256 + t];
    acc[labs[r]][t] += ivl[r] * x;
  }
  __syncthreads();
#pragma unroll
  for (int m = 0; m < 6; ++m) atomicAdd(&out[m * 256 + t], acc[m][t]);
}

// ===== A_coarse = P^T A P : per-row neighbor-label counts from bit rows =====
__global__ __launch_bounds__(256) void k_acoarse(const u64* __restrict__ bits,
                                                 const int* __restrict__ labels,
                                                 const float* __restrict__ invs, float* out) {
  __shared__ unsigned char labs[NN];   // 4 KiB
  __shared__ float accA[36];
  __shared__ float ivsl[8];
  int t = threadIdx.x;
  for (int v = t; v < NN; v += 256) labs[v] = (unsigned char)labels[v];
  if (t < 36) accA[t] = 0.0f;
  if (t < 6) ivsl[t] = invs[t];
  __syncthreads();
  int i = blockIdx.x * 256 + t;
  u64 cnt = 0;   // six 10-bit counters
  const u64* row = bits + (size_t)i * NCH;
  for (int c = 0; c < NCH; ++c) {
    u64 wm = row[c];
    while (wm) {
      int j = (c << 6) + __builtin_ctzll(wm);
      wm &= wm - 1;
      cnt += 1ull << (labs[j] * 10);
    }
  }
  int li = labs[i];
  float fi = ivsl[li];
#pragma unroll
  for (int b = 0; b < 6; ++b) {
    float cb = (float)((cnt >> (b * 10)) & 1023ull);
    if (cb != 0.0f) atomicAdd(&accA[li * 6 + b], fi * ivsl[b] * cb);
  }
  __syncthreads();
  if (t < 36) atomicAdd(&out[1536 + t], accA[t]);
}

// ============================ launch ============================
extern "C" void kernel_launch(void* const* d_in, const int* in_sizes, int n_in,
                              void* d_out, int out_size, void* d_ws, size_t ws_size,
                              hipStream_t stream) {
  const float* X = (const float*)d_in[0];
  const float* A = (const float*)d_in[1];
  float* out = (float*)d_out;

  char* wp = (char*)d_ws;
  size_t off = 0;
#define WALLOC(ty, name, count) \
  ty* name = (ty*)(wp + off);   \
  off += (((size_t)(count) * sizeof(ty)) + 255) & ~(size_t)255;
  WALLOC(u64, bits, (size_t)NN * NCH)      // 2 MiB
  WALLOC(u16, inter, (size_t)NN * NN)      // 32 MiB
  WALLOC(u16, deg, NN)
  WALLOC(int, comp, NN)
  WALLOC(u64, nkey, NN)
  WALLOC(int, nu, NN)
  WALLOC(u64, mkey, 4352)
  WALLOC(int, mi, 4352)
  WALLOC(int, mj, 4352)
  WALLOC(int, labels, NN)
  WALLOC(float, invs, 8)
  WALLOC(int, ncomp, 1)
  WALLOC(int, mstcnt, 1)
#undef WALLOC
  if (off > ws_size) return;   // workspace too small: leave output zeroed (clean fail)

  k_init<<<64, 256, 0, stream>>>(out, out_size, comp, ncomp, mstcnt);
  k_packdeg<<<NN / 4, 256, 0, stream>>>(A, bits, deg);
  k_inter<<<2080, 256, 0, stream>>>(bits, inter);
  for (int ph = 0; ph < 12; ++ph) {
    k_scan<<<NN / 16, 256, 0, stream>>>(inter, deg, comp, ncomp, nkey, nu);
    k_merge<<<1, 1024, 0, stream>>>(nkey, nu, comp, ncomp, mstcnt, mkey, mi, mj);
  }
  k_finalize<<<1, 1024, 0, stream>>>(mkey, mi, mj, mstcnt, labels, invs, out);
  k_xcoarse<<<64, 256, 0, stream>>>(X, labels, invs, out);
  k_acoarse<<<16, 256, 0, stream>>>(bits, labels, invs, out);
}

// Round 5
// 424.098 us; speedup vs baseline: 2.8578x; 1.0763x over previous
//
#include <hip/hip_runtime.h>

typedef unsigned long long u64;
typedef unsigned short u16;

#define NN 4096
#define NCH 64          // u64 chunks per bit-row
#define NSUP 6

// ============================ init ============================
__global__ void k_init(float* out, int out_n, int* comp, int* ncomp, int* mstcnt) {
  int t = blockIdx.x * blockDim.x + threadIdx.x;
  int nt = gridDim.x * blockDim.x;
  for (int v = t; v < NN; v += nt) comp[v] = v;
  for (int i = t; i < out_n; i += nt) out[i] = 0.0f;
  if (t == 0) { *ncomp = NN; *mstcnt = 0; }
}

// ============ pack A rows into bits + degree (fused, ballot) ============
__global__ __launch_bounds__(256) void k_packdeg(const float* __restrict__ A,
                                                 u64* __restrict__ bits,
                                                 u16* __restrict__ deg) {
  int t = threadIdx.x;
  int w = t >> 6, lane = t & 63;
  int row = blockIdx.x * 4 + w;
  const float* rp = A + (size_t)row * NN;
  u64 my = 0;
  int dsum = 0;
#pragma unroll 8
  for (int k = 0; k < 64; ++k) {
    float v = rp[k * 64 + lane];
    u64 m = __ballot(v > 0.0f);
    dsum += __popcll(m);
    if (lane == k) my = m;
  }
  bits[(size_t)row * NCH + lane] = my;
  if (lane == 0) deg[row] = (u16)dsum;
}

// ========== inter[i][j] = |N(i) & N(j)| via popcount GEMM ==========
// 128x128 block tile, 8x8 per thread (VALU-bound, not LDS-issue-bound).
// Triangular grid 528 blocks; 2-stage K-split; swizzle sw(r)=((r>>3)^r)&7:
// av reads broadcast across 4 groups (free), bv reads 2-way (free).
__global__ __launch_bounds__(256) void k_inter(const u64* __restrict__ bits,
                                               u16* __restrict__ inter) {
  __shared__ ulonglong2 L[2][128 * 16];   // 64 KiB
  int b = blockIdx.x;
  // decode b -> (by, bx), 0<=by<=bx<32 ; CUM(y) = 32y - y(y-1)/2
  int by = (int)((65.0f - sqrtf(4225.0f - 8.0f * (float)b)) * 0.5f) - 1;
  if (by < 0) by = 0;
#define CUM(y) (32 * (y) - ((y) * ((y) - 1)) / 2)
  while (by < 31 && CUM(by + 1) <= b) ++by;
  while (CUM(by) > b) --by;
  int bx = by + (b - CUM(by));
#undef CUM
  int i0 = by * 128, j0 = bx * 128;
  int t = threadIdx.x;
  int tx = t & 15, ty = t >> 4;
  int swA[8], swB[8];
#pragma unroll
  for (int a = 0; a < 8; ++a) {
    int rA = ty * 8 + a, rB = tx * 8 + a;
    swA[a] = ((rA >> 3) ^ rA) & 7;
    swB[a] = ((rB >> 3) ^ rB) & 7;
  }
  int slotL = t & 15, rowgL = t >> 4;      // staging: 16 slots x 16 row-groups
  int acc[8][8] = {};
  for (int st = 0; st < 2; ++st) {
    __syncthreads();
#pragma unroll
    for (int rr = 0; rr < 8; ++rr) {
      int row = rowgL * 8 + rr;
      int sw = ((row >> 3) ^ row) & 7;
      L[0][row * 16 + (slotL ^ sw)] =
          reinterpret_cast<const ulonglong2*>(bits + (size_t)(i0 + row) * NCH)[st * 16 + slotL];
      L[1][row * 16 + (slotL ^ sw)] =
          reinterpret_cast<const ulonglong2*>(bits + (size_t)(j0 + row) * NCH)[st * 16 + slotL];
    }
    __syncthreads();
    for (int s = 0; s < 16; ++s) {
      ulonglong2 av[8], bv[8];
#pragma unroll
      for (int a = 0; a < 8; ++a) av[a] = L[0][(ty * 8 + a) * 16 + (s ^ swA[a])];
#pragma unroll
      for (int c = 0; c < 8; ++c) bv[c] = L[1][(tx * 8 + c) * 16 + (s ^ swB[c])];
#pragma unroll
      for (int a = 0; a < 8; ++a)
#pragma unroll
        for (int c = 0; c < 8; ++c)
          acc[a][c] += __popcll(av[a].x & bv[c].x) + __popcll(av[a].y & bv[c].y);
    }
  }
#pragma unroll
  for (int a = 0; a < 8; ++a) {            // direct tile [i][j], one 16B store
    int i = i0 + ty * 8 + a;
    uint4 wv;
    wv.x = (unsigned)acc[a][0] | ((unsigned)acc[a][1] << 16);
    wv.y = (unsigned)acc[a][2] | ((unsigned)acc[a][3] << 16);
    wv.z = (unsigned)acc[a][4] | ((unsigned)acc[a][5] << 16);
    wv.w = (unsigned)acc[a][6] | ((unsigned)acc[a][7] << 16);
    *reinterpret_cast<uint4*>(inter + (size_t)i * NN + j0 + tx * 8) = wv;
  }
  if (bx != by) {
#pragma unroll
    for (int c = 0; c < 8; ++c) {          // mirror tile [j][i]
      int j = j0 + tx * 8 + c;
      uint4 wv;
      wv.x = (unsigned)acc[0][c] | ((unsigned)acc[1][c] << 16);
      wv.y = (unsigned)acc[2][c] | ((unsigned)acc[3][c] << 16);
      wv.z = (unsigned)acc[4][c] | ((unsigned)acc[5][c] << 16);
      wv.w = (unsigned)acc[6][c] | ((unsigned)acc[7][c] << 16);
      *reinterpret_cast<uint4*>(inter + (size_t)j * NN + i0 + ty * 8) = wv;
    }
  }
}

// ===== Boruvka phase A: per-node best outgoing edge (one WAVE per row) =====
// 4 rows/block, 1024 blocks (max TLP). Branch-free u64 key max.
// node-local order: (sim desc, partner u asc) == (sim desc, pair-index asc)
__global__ __launch_bounds__(256) void k_scan(const u16* __restrict__ inter,
                                              const u16* __restrict__ deg,
                                              const int* __restrict__ comp,
                                              const int* __restrict__ ncomp,
                                              u64* __restrict__ nkey,
                                              int* __restrict__ nu) {
  if (*ncomp <= 1) return;
  __shared__ int comp_s[NN];   // 16 KiB
  __shared__ u16 deg_s[NN];    // 8 KiB
  int t = threadIdx.x;
  for (int i = t; i < NN / 4; i += 256)
    reinterpret_cast<int4*>(comp_s)[i] = reinterpret_cast<const int4*>(comp)[i];
  for (int i = t; i < NN / 8; i += 256)
    reinterpret_cast<uint4*>(deg_s)[i] = reinterpret_cast<const uint4*>(deg)[i];
  __syncthreads();
  int w = t >> 6, lane = t & 63;
  int v = blockIdx.x * 4 + w;
  int cv = comp_s[v];
  int dv = (int)deg_s[v];
  const u16* row = inter + (size_t)v * NN;
  u64 key = 0;
  for (int it = 0; it < 8; ++it) {
    int ub = it * 512 + lane * 8;
    uint4 pv = *reinterpret_cast<const uint4*>(row + ub);          // 8x u16 inter
    uint4 dg = *reinterpret_cast<const uint4*>(deg_s + ub);        // 8x u16 deg
    int4 c0 = reinterpret_cast<const int4*>(comp_s)[ub >> 2];
    int4 c1 = reinterpret_cast<const int4*>(comp_s)[(ub >> 2) + 1];
    unsigned pw[4] = { pv.x, pv.y, pv.z, pv.w };
    unsigned dw[4] = { dg.x, dg.y, dg.z, dg.w };
    int cs_[8] = { c0.x, c0.y, c0.z, c0.w, c1.x, c1.y, c1.z, c1.w };
#pragma unroll
    for (int k = 0; k < 8; ++k) {
      int iv = (int)((pw[k >> 1] >> ((k & 1) * 16)) & 0xFFFF);
      int du = (int)((dw[k >> 1] >> ((k & 1) * 16)) & 0xFFFF);
      int un = dv + du - iv;
      float s = (un > 0) ? ((float)iv / (float)un) : 0.0f;         // exact fp32 div == numpy
      unsigned sb = __float_as_uint(s);
      u64 kk = (cs_[k] != cv)
                   ? (((u64)sb << 32) | (u64)(0xFFFFFFFFu - (unsigned)(ub + k)))
                   : 0ull;
      if (kk > key) key = kk;
    }
  }
#pragma unroll
  for (int off = 32; off > 0; off >>= 1) {                          // wave max-reduce
    unsigned lo = (unsigned)key, hi = (unsigned)(key >> 32);
    unsigned olo = __shfl_xor(lo, off, 64), ohi = __shfl_xor(hi, off, 64);
    u64 o = ((u64)ohi << 32) | (u64)olo;
    if (o > key) key = o;
  }
  if (lane == 0) {
    u64 pk = 0; int u = -1;
    if (key != 0ull) {
      unsigned simb = (unsigned)(key >> 32);
      u = (int)(0xFFFFFFFFu - (unsigned)(key & 0xFFFFFFFFull));
      int i = v < u ? v : u, j = v < u ? u : v;
      unsigned idx = (unsigned)i * (unsigned)(2 * NN - i - 1) / 2u + (unsigned)(j - i - 1);
      pk = ((u64)simb << 24) | (u64)(0xFFFFFFu - idx);              // global pair key
    }
    nkey[v] = pk; nu[v] = u;
  }
}

// ===== Boruvka phase B: component-best, hook, 2-cycle break, jump (LDS) =====
__global__ __launch_bounds__(1024) void k_merge(const u64* __restrict__ nkey,
                                                const int* __restrict__ nu,
                                                int* comp, int* ncomp, int* mstcnt,
                                                u64* mkey, int* mi, int* mj) {
  if (*ncomp <= 1) return;
  __shared__ int parent_s[NN];        // 16 KiB
  __shared__ u64 cbest_s[NN];         // 32 KiB
  __shared__ unsigned char mk_s[NN];  // 4 KiB
  __shared__ int cnt_s, chg_s;
  int t = threadIdx.x;
  for (int c = t; c < NN; c += 1024) { parent_s[c] = c; cbest_s[c] = 0ull; }
  __syncthreads();
  for (int v = t; v < NN; v += 1024) {
    u64 k = nkey[v];
    if (k) atomicMax(&cbest_s[comp[v]], k);
  }
  __syncthreads();
  for (int v = t; v < NN; v += 1024) {
    u64 k = nkey[v];
    if (!k) continue;
    int c = comp[v];
    if (k == cbest_s[c]) {
      int u = nu[v];
      int cu = comp[u];
      bool mutual = (cbest_s[cu] == k);
      if (!mutual || v < u) {
        int slot = atomicAdd(mstcnt, 1);
        if (slot < 4352) { mkey[slot] = k; mi[slot] = v; mj[slot] = u; }
      }
      parent_s[c] = cu;                // one winner per component
    }
  }
  __syncthreads();
  for (int c = t; c < NN; c += 1024) { // break mutual 2-cycles: keep smaller root
    int pc = parent_s[c];
    if (parent_s[pc] == c && c < pc) parent_s[c] = c;
  }
  __syncthreads();
  for (int it = 0; it < 13; ++it) {    // pointer jumping w/ convergence check
    if (t == 0) chg_s = 0;
    __syncthreads();
    for (int c = t; c < NN; c += 1024) {
      int p1 = parent_s[c], p2 = parent_s[p1];
      if (p1 != p2) { parent_s[c] = p2; chg_s = 1; }
    }
    __syncthreads();
    if (!chg_s) break;
  }
  for (int c = t; c < NN; c += 1024) mk_s[c] = 0;
  if (t == 0) cnt_s = 0;
  __syncthreads();
  for (int v = t; v < NN; v += 1024) {
    int nc = parent_s[comp[v]];
    comp[v] = nc;
    mk_s[nc] = 1;
  }
  __syncthreads();
  int lc = 0;
  for (int c = t; c < NN; c += 1024) lc += mk_s[c];
  atomicAdd(&cnt_s, lc);
  __syncthreads();
  if (t == 0) *ncomp = cnt_s;
}

// ===== finalize: drop 5 smallest MST edges, CC, labels, P =====
__global__ __launch_bounds__(1024) void k_finalize(u64* mkey, const int* __restrict__ mi,
                                                   const int* __restrict__ mj,
                                                   const int* __restrict__ mstcnt,
                                                   int* labels_g, float* invs_g, float* out) {
  __shared__ int p[NN];        // 16 KiB
  __shared__ int rr[NN];       // 16 KiB (root -> rank LUT)
  __shared__ u64 rk[1024];
  __shared__ int rs[1024];
  __shared__ int roots[16];
  __shared__ int rcnt;
  __shared__ int szs[8];
  __shared__ float ivs[8];
  __shared__ int changed;
  int t = threadIdx.x;
  int nm = *mstcnt;            // 4095 expected
  if (nm < 0) nm = 0;          // defensive clamps (poison guard)
  if (nm > 4352) nm = 4352;
  for (int v = t; v < NN; v += 1024) p[v] = v;
  // remove the 5 smallest edges (smallest keys == lowest sim / largest pair-idx)
  for (int pass = 0; pass < NSUP - 1; ++pass) {
    u64 bk = ~0ull; int bs = -1;
    for (int e = t; e < nm; e += 1024) { u64 k = mkey[e]; if (k < bk) { bk = k; bs = e; } }
    rk[t] = bk; rs[t] = bs;
    __syncthreads();
    for (int s = 512; s > 0; s >>= 1) {
      if (t < s && rk[t + s] < rk[t]) { rk[t] = rk[t + s]; rs[t] = rs[t + s]; }
      __syncthreads();
    }
    if (t == 0 && rs[0] >= 0) mkey[rs[0]] = ~0ull;   // mark removed
    __syncthreads();
  }
  // connected components over kept edges (min-label hook + jump)
  for (int round = 0; round < 64; ++round) {
    if (t == 0) changed = 0;
    __syncthreads();
    for (int e = t; e < nm; e += 1024) {
      if (mkey[e] == ~0ull) continue;
      int a = p[mi[e]], b = p[mj[e]];
      if (a == b) continue;
      int m = a < b ? a : b, M = a < b ? b : a;
      int old = atomicMin(&p[M], m);
      if (old > m) changed = 1;
    }
    __syncthreads();
    for (int rep = 0; rep < 3; ++rep) {
      for (int v = t; v < NN; v += 1024) p[v] = p[p[v]];
      __syncthreads();
    }
    int ch = changed;
    __syncthreads();
    if (!ch) break;
  }
  for (int rep = 0; rep < 13; ++rep) {   // full compression -> p[v] = component min index
    for (int v = t; v < NN; v += 1024) p[v] = p[p[v]];
    __syncthreads();
  }
  if (t == 0) rcnt = 0;
  __syncthreads();
  for (int v = t; v < NN; v += 1024)
    if (p[v] == v) { int s = atomicAdd(&rcnt, 1); if (s < 16) roots[s] = v; }
  __syncthreads();
  if (t == 0) {                           // sort roots asc -> first-occurrence label order
    int c = rcnt > 16 ? 16 : rcnt;
    for (int a = 1; a < c; ++a) {
      int x = roots[a]; int b = a - 1;
      while (b >= 0 && roots[b] > x) { roots[b + 1] = roots[b]; --b; }
      roots[b + 1] = x;
    }
  }
  if (t < 8) szs[t] = 0;
  __syncthreads();
  if (t < rcnt && t < 16) rr[roots[t]] = t;
  __syncthreads();
  for (int v = t; v < NN; v += 1024) {
    int lab = rr[p[v]];
    labels_g[v] = lab;
    atomicAdd(&szs[lab], 1);
  }
  __syncthreads();
  if (t < rcnt && t < 8) {
    float iv = 1.0f / sqrtf((float)szs[t] + 1e-10f);   // bit-matches reference P entries
    ivs[t] = iv; invs_g[t] = iv;
  }
  __syncthreads();
  for (int v = t; v < NN; v += 1024) {                 // P at out+1572, row-major [4096][6]
    int lab = rr[p[v]];
    float* base = out + 1572 + v * 6;
#pragma unroll
    for (int b = 0; b < 6; ++b) base[b] = (b == lab) ? ivs[lab] : 0.0f;
  }
}

// ===== X_coarse = P^T X : label-indexed column sums =====
__global__ __launch_bounds__(256) void k_xcoarse(const float* __restrict__ X,
                                                 const int* __restrict__ labels,
                                                 const float* __restrict__ invs, float* out) {
  __shared__ float acc[6][256];
  __shared__ int labs[64];
  __shared__ float ivl[64];
  int t = threadIdx.x;
#pragma unroll
  for (int m = 0; m < 6; ++m) acc[m][t] = 0.0f;
  if (t < 64) { int v = blockIdx.x * 64 + t; int l = labels[v]; labs[t] = l; ivl[t] = invs[l]; }
  __syncthreads();
  int v0 = blockIdx.x * 64;
  for (int r = 0; r < 64; ++r) {
    float x = X[(size_t)(v0 + r) * 256 + t];
    acc[labs[r]][t] += ivl[r] * x;
  }
  __syncthreads();
#pragma unroll
  for (int m = 0; m < 6; ++m) atomicAdd(&out[m * 256 + t], acc[m][t]);
}

// ===== A_coarse = P^T A P : per-row neighbor-label counts from bit rows =====
__global__ __launch_bounds__(256) void k_acoarse(const u64* __restrict__ bits,
                                                 const int* __restrict__ labels,
                                                 const float* __restrict__ invs, float* out) {
  __shared__ unsigned char labs[NN];   // 4 KiB
  __shared__ float accA[36];
  __shared__ float ivsl[8];
  int t = threadIdx.x;
  for (int v = t; v < NN; v += 256) labs[v] = (unsigned char)labels[v];
  if (t < 36) accA[t] = 0.0f;
  if (t < 6) ivsl[t] = invs[t];
  __syncthreads();
  int i = blockIdx.x * 256 + t;
  u64 cnt = 0;   // six 10-bit counters
  const u64* row = bits + (size_t)i * NCH;
  for (int c = 0; c < NCH; ++c) {
    u64 wm = row[c];
    while (wm) {
      int j = (c << 6) + __builtin_ctzll(wm);
      wm &= wm - 1;
      cnt += 1ull << (labs[j] * 10);
    }
  }
  int li = labs[i];
  float fi = ivsl[li];
#pragma unroll
  for (int b = 0; b < 6; ++b) {
    float cb = (float)((cnt >> (b * 10)) & 1023ull);
    if (cb != 0.0f) atomicAdd(&accA[li * 6 + b], fi * ivsl[b] * cb);
  }
  __syncthreads();
  if (t < 36) atomicAdd(&out[1536 + t], accA[t]);
}

// ============================ launch ============================
extern "C" void kernel_launch(void* const* d_in, const int* in_sizes, int n_in,
                              void* d_out, int out_size, void* d_ws, size_t ws_size,
                              hipStream_t stream) {
  const float* X = (const float*)d_in[0];
  const float* A = (const float*)d_in[1];
  float* out = (float*)d_out;

  char* wp = (char*)d_ws;
  size_t off = 0;
#define WALLOC(ty, name, count) \
  ty* name = (ty*)(wp + off);   \
  off += (((size_t)(count) * sizeof(ty)) + 255) & ~(size_t)255;
  WALLOC(u64, bits, (size_t)NN * NCH)      // 2 MiB
  WALLOC(u16, inter, (size_t)NN * NN)      // 32 MiB
  WALLOC(u16, deg, NN)
  WALLOC(int, comp, NN)
  WALLOC(u64, nkey, NN)
  WALLOC(int, nu, NN)
  WALLOC(u64, mkey, 4352)
  WALLOC(int, mi, 4352)
  WALLOC(int, mj, 4352)
  WALLOC(int, labels, NN)
  WALLOC(float, invs, 8)
  WALLOC(int, ncomp, 1)
  WALLOC(int, mstcnt, 1)
#undef WALLOC
  if (off > ws_size) return;   // workspace too small: leave output zeroed (clean fail)

  k_init<<<64, 256, 0, stream>>>(out, out_size, comp, ncomp, mstcnt);
  k_packdeg<<<NN / 4, 256, 0, stream>>>(A, bits, deg);
  k_inter<<<528, 256, 0, stream>>>(bits, inter);
  for (int ph = 0; ph < 12; ++ph) {
    k_scan<<<NN / 4, 256, 0, stream>>>(inter, deg, comp, ncomp, nkey, nu);
    k_merge<<<1, 1024, 0, stream>>>(nkey, nu, comp, ncomp, mstcnt, mkey, mi, mj);
  }
  k_finalize<<<1, 1024, 0, stream>>>(mkey, mi, mj, mstcnt, labels, invs, out);
  k_xcoarse<<<64, 256, 0, stream>>>(X, labels, invs, out);
  k_acoarse<<<16, 256, 0, stream>>>(bits, labels, invs, out);
}

// Round 6
// 381.936 us; speedup vs baseline: 3.1732x; 1.1104x over previous
//
#include <hip/hip_runtime.h>

typedef unsigned long long u64;
typedef unsigned short u16;

#define NN 4096
#define NCH 64          // u64 chunks per bit-row
#define NSUP 6

// ========= pack A rows into bits + degree (ballot) + all init, fused =========
// 1024 blocks x 256 threads; one wave per row.
__global__ __launch_bounds__(256) void k_packdeg(const float* __restrict__ A,
                                                 u64* __restrict__ bits,
                                                 u16* __restrict__ deg,
                                                 float* out, int out_n,
                                                 int* comp, int* ncomp, int* mstcnt) {
  int t = threadIdx.x;
  int w = t >> 6, lane = t & 63;
  int row = blockIdx.x * 4 + w;
  const float* rp = A + (size_t)row * NN;
  u64 my = 0;
  int dsum = 0;
#pragma unroll 8
  for (int k = 0; k < 64; ++k) {
    float v = rp[k * 64 + lane];
    u64 m = __ballot(v > 0.0f);
    dsum += __popcll(m);
    if (lane == k) my = m;
  }
  bits[(size_t)row * NCH + lane] = my;
  if (lane == 0) deg[row] = (u16)dsum;
  // fused init
  int g = blockIdx.x * 256 + t;
  if (g < out_n) out[g] = 0.0f;            // out_n = 26148 < 262144
  if (g < NN) comp[g] = g;
  if (g == 0) { *ncomp = NN; *mstcnt = 0; }
}

// ========== inter[i][j] = |N(i) & N(j)| via popcount GEMM ==========
// 64x64 tile, 4x4/thread (R4 shape, 90us proven), 4-stage K-split -> 16KiB LDS
// (8 blocks/CU vs R4's 5). Swizzle sw(r)=(r>>2)&7 for 8-slot rows:
// staging writes at 8-lane/16B floor, av reads broadcast, bv reads 2-way free.
__global__ __launch_bounds__(256) void k_inter(const u64* __restrict__ bits,
                                               u16* __restrict__ inter) {
  __shared__ ulonglong2 L[2][64 * 8];   // 16 KiB
  int b = blockIdx.x;
  // decode b -> (by, bx), by<=bx<64 ; CUM(y) = 64y - y(y-1)/2  (2080 blocks)
  int by = (int)((129.0f - sqrtf(16641.0f - 8.0f * (float)b)) * 0.5f) - 1;
  if (by < 0) by = 0;
#define CUM(y) (64 * (y) - ((y) * ((y) - 1)) / 2)
  while (by < 63 && CUM(by + 1) <= b) ++by;
  while (CUM(by) > b) --by;
  int bx = by + (b - CUM(by));
#undef CUM
  int i0 = by * 64, j0 = bx * 64;
  int t = threadIdx.x;
  int tx = t & 15, ty = t >> 4;
  int swA = ty & 7, swB = tx & 7;          // (row>>2)&7 with row=ty*4+a / tx*4+b
  int slotL = t & 7, rowL = t >> 3;        // staging: 8 slots x 32 rows (x2 passes)
  int sw0 = (rowL >> 2) & 7, sw1 = ((rowL + 32) >> 2) & 7;
  int acc[4][4] = {};
  for (int st = 0; st < 4; ++st) {
    __syncthreads();
    {
      const ulonglong2* gi0 = reinterpret_cast<const ulonglong2*>(bits + (size_t)(i0 + rowL) * NCH);
      const ulonglong2* gi1 = reinterpret_cast<const ulonglong2*>(bits + (size_t)(i0 + rowL + 32) * NCH);
      const ulonglong2* gj0 = reinterpret_cast<const ulonglong2*>(bits + (size_t)(j0 + rowL) * NCH);
      const ulonglong2* gj1 = reinterpret_cast<const ulonglong2*>(bits + (size_t)(j0 + rowL + 32) * NCH);
      L[0][rowL * 8 + (slotL ^ sw0)] = gi0[st * 8 + slotL];
      L[0][(rowL + 32) * 8 + (slotL ^ sw1)] = gi1[st * 8 + slotL];
      L[1][rowL * 8 + (slotL ^ sw0)] = gj0[st * 8 + slotL];
      L[1][(rowL + 32) * 8 + (slotL ^ sw1)] = gj1[st * 8 + slotL];
    }
    __syncthreads();
    for (int s = 0; s < 8; ++s) {
      ulonglong2 av[4], bv[4];
#pragma unroll
      for (int a = 0; a < 4; ++a) av[a] = L[0][(ty * 4 + a) * 8 + (s ^ swA)];
#pragma unroll
      for (int c = 0; c < 4; ++c) bv[c] = L[1][(tx * 4 + c) * 8 + (s ^ swB)];
#pragma unroll
      for (int a = 0; a < 4; ++a)
#pragma unroll
        for (int c = 0; c < 4; ++c)
          acc[a][c] += __popcll(av[a].x & bv[c].x) + __popcll(av[a].y & bv[c].y);
    }
  }
#pragma unroll
  for (int a = 0; a < 4; ++a) {            // direct tile [i][j]
    int i = i0 + ty * 4 + a;
    ushort4 wv;
    wv.x = (u16)acc[a][0]; wv.y = (u16)acc[a][1];
    wv.z = (u16)acc[a][2]; wv.w = (u16)acc[a][3];
    *reinterpret_cast<ushort4*>(inter + (size_t)i * NN + j0 + tx * 4) = wv;
  }
  if (bx != by) {
#pragma unroll
    for (int c = 0; c < 4; ++c) {          // mirror tile [j][i]
      int j = j0 + tx * 4 + c;
      ushort4 wv;
      wv.x = (u16)acc[0][c]; wv.y = (u16)acc[1][c];
      wv.z = (u16)acc[2][c]; wv.w = (u16)acc[3][c];
      *reinterpret_cast<ushort4*>(inter + (size_t)j * NN + i0 + ty * 4) = wv;
    }
  }
}

// ===== Boruvka phase A: per-node best outgoing edge (one WAVE per row) =====
// 4 rows/block, 1024 blocks. comp staged as u16 -> 2 LDS reads per 8 elems.
// node-local order: (sim desc, partner u asc) == (sim desc, pair-index asc)
__global__ __launch_bounds__(256) void k_scan(const u16* __restrict__ inter,
                                              const u16* __restrict__ deg,
                                              const int* __restrict__ comp,
                                              const int* __restrict__ ncomp,
                                              u64* __restrict__ nkey,
                                              int* __restrict__ nu) {
  if (*ncomp <= 1) return;
  __shared__ u16 comp_s[NN];   // 8 KiB
  __shared__ u16 deg_s[NN];    // 8 KiB
  int t = threadIdx.x;
  for (int i = t; i < NN / 8; i += 256) {
    int4 ca = reinterpret_cast<const int4*>(comp)[i * 2];
    int4 cb = reinterpret_cast<const int4*>(comp)[i * 2 + 1];
    uint4 pk;
    pk.x = (unsigned)ca.x | ((unsigned)ca.y << 16);
    pk.y = (unsigned)ca.z | ((unsigned)ca.w << 16);
    pk.z = (unsigned)cb.x | ((unsigned)cb.y << 16);
    pk.w = (unsigned)cb.z | ((unsigned)cb.w << 16);
    reinterpret_cast<uint4*>(comp_s)[i] = pk;
    reinterpret_cast<uint4*>(deg_s)[i] = reinterpret_cast<const uint4*>(deg)[i];
  }
  __syncthreads();
  int w = t >> 6, lane = t & 63;
  int v = blockIdx.x * 4 + w;
  int cv = (int)comp_s[v];
  int dv = (int)deg_s[v];
  const u16* row = inter + (size_t)v * NN;
  u64 key = 0;
  for (int it = 0; it < 8; ++it) {
    int ub = it * 512 + lane * 8;
    uint4 pv = *reinterpret_cast<const uint4*>(row + ub);              // 8x u16 inter
    uint4 dg = reinterpret_cast<const uint4*>(deg_s)[ub >> 3];         // 8x u16 deg
    uint4 cs = reinterpret_cast<const uint4*>(comp_s)[ub >> 3];        // 8x u16 comp
    unsigned pw[4] = { pv.x, pv.y, pv.z, pv.w };
    unsigned dw[4] = { dg.x, dg.y, dg.z, dg.w };
    unsigned cw[4] = { cs.x, cs.y, cs.z, cs.w };
#pragma unroll
    for (int k = 0; k < 8; ++k) {
      int iv = (int)((pw[k >> 1] >> ((k & 1) * 16)) & 0xFFFF);
      int du = (int)((dw[k >> 1] >> ((k & 1) * 16)) & 0xFFFF);
      int cu = (int)((cw[k >> 1] >> ((k & 1) * 16)) & 0xFFFF);
      int un = dv + du - iv;
      float s = (un > 0) ? ((float)iv / (float)un) : 0.0f;             // exact fp32 div == numpy
      unsigned sb = __float_as_uint(s);
      u64 kk = (cu != cv)
                   ? (((u64)sb << 32) | (u64)(0xFFFFFFFFu - (unsigned)(ub + k)))
                   : 0ull;
      if (kk > key) key = kk;
    }
  }
#pragma unroll
  for (int off = 32; off > 0; off >>= 1) {                              // wave max-reduce
    unsigned lo = (unsigned)key, hi = (unsigned)(key >> 32);
    unsigned olo = __shfl_xor(lo, off, 64), ohi = __shfl_xor(hi, off, 64);
    u64 o = ((u64)ohi << 32) | (u64)olo;
    if (o > key) key = o;
  }
  if (lane == 0) {
    u64 pk = 0; int u = -1;
    if (key != 0ull) {
      unsigned simb = (unsigned)(key >> 32);
      u = (int)(0xFFFFFFFFu - (unsigned)(key & 0xFFFFFFFFull));
      int i = v < u ? v : u, j = v < u ? u : v;
      unsigned idx = (unsigned)i * (unsigned)(2 * NN - i - 1) / 2u + (unsigned)(j - i - 1);
      pk = ((u64)simb << 24) | (u64)(0xFFFFFFu - idx);                  // global pair key
    }
    nkey[v] = pk; nu[v] = u;
  }
}

// ===== Boruvka phase B: comp-best, hook, 2-cycle break, jump (LDS) =====
// When the component count reaches 1, runs the finalize (drop-5, CC, labels, P)
// in the same launch -- exactly once, deterministic.
__global__ __launch_bounds__(1024) void k_merge(const u64* __restrict__ nkey,
                                                const int* __restrict__ nu,
                                                int* comp, int* ncomp, int* mstcnt,
                                                u64* mkey, int* mi, int* mj,
                                                int* labels_g, float* invs_g, float* out) {
  if (*ncomp <= 1) return;
  __shared__ int parent_s[NN];        // 16 KiB (also finalize's p[])
  __shared__ u64 cbest_s[NN];         // 32 KiB (finalize aliases rr/rk/rs here)
  __shared__ unsigned char mk_s[NN];  // 4 KiB
  __shared__ int roots[16];
  __shared__ int rcnt, cnt_s, chg_s, changed;
  __shared__ int szs[8];
  __shared__ float ivs[8];
  int t = threadIdx.x;
  for (int c = t; c < NN; c += 1024) { parent_s[c] = c; cbest_s[c] = 0ull; }
  __syncthreads();
  for (int v = t; v < NN; v += 1024) {
    u64 k = nkey[v];
    if (k) atomicMax(&cbest_s[comp[v]], k);
  }
  __syncthreads();
  for (int v = t; v < NN; v += 1024) {
    u64 k = nkey[v];
    if (!k) continue;
    int c = comp[v];
    if (k == cbest_s[c]) {
      int u = nu[v];
      int cu = comp[u];
      bool mutual = (cbest_s[cu] == k);
      if (!mutual || v < u) {
        int slot = atomicAdd(mstcnt, 1);
        if (slot < 4352) { mkey[slot] = k; mi[slot] = v; mj[slot] = u; }
      }
      parent_s[c] = cu;                // one winner per component (keys unique)
    }
  }
  __syncthreads();
  for (int c = t; c < NN; c += 1024) { // break mutual 2-cycles: keep smaller root
    int pc = parent_s[c];
    if (parent_s[pc] == c && c < pc) parent_s[c] = c;
  }
  __syncthreads();
  for (int it = 0; it < 13; ++it) {    // pointer jumping w/ convergence check
    if (t == 0) chg_s = 0;
    __syncthreads();
    for (int c = t; c < NN; c += 1024) {
      int p1 = parent_s[c], p2 = parent_s[p1];
      if (p1 != p2) { parent_s[c] = p2; chg_s = 1; }
    }
    __syncthreads();
    if (!chg_s) break;
  }
  for (int c = t; c < NN; c += 1024) mk_s[c] = 0;
  if (t == 0) cnt_s = 0;
  __syncthreads();
  for (int v = t; v < NN; v += 1024) {
    int nc = parent_s[comp[v]];
    comp[v] = nc;
    mk_s[nc] = 1;
  }
  __syncthreads();
  int lc = 0;
  for (int c = t; c < NN; c += 1024) lc += mk_s[c];
  atomicAdd(&cnt_s, lc);
  __syncthreads();
  if (t == 0) *ncomp = cnt_s;
  __syncthreads();
  if (cnt_s != 1) return;
  // ================== finalize (runs exactly once) ==================
  int* rr = reinterpret_cast<int*>(cbest_s);          // 16 KiB: root->rank LUT
  u64* rk = cbest_s + 2048;                           // 8 KiB: reduce keys
  int* rs = reinterpret_cast<int*>(cbest_s + 3072);   // 4 KiB: reduce idx
  int nm = *mstcnt;            // 4095 expected
  if (nm < 0) nm = 0;
  if (nm > 4352) nm = 4352;
  for (int v = t; v < NN; v += 1024) parent_s[v] = v;
  // remove the 5 smallest edges (lowest sim / largest pair-idx first)
  for (int pass = 0; pass < NSUP - 1; ++pass) {
    u64 bk = ~0ull; int bsel = -1;
    for (int e = t; e < nm; e += 1024) { u64 k = mkey[e]; if (k < bk) { bk = k; bsel = e; } }
    rk[t] = bk; rs[t] = bsel;
    __syncthreads();
    for (int s = 512; s > 0; s >>= 1) {
      if (t < s && rk[t + s] < rk[t]) { rk[t] = rk[t + s]; rs[t] = rs[t + s]; }
      __syncthreads();
    }
    if (t == 0 && rs[0] >= 0) mkey[rs[0]] = ~0ull;    // mark removed
    __syncthreads();
  }
  // connected components over kept edges (min-label hook + jump)
  for (int round = 0; round < 64; ++round) {
    if (t == 0) changed = 0;
    __syncthreads();
    for (int e = t; e < nm; e += 1024) {
      if (mkey[e] == ~0ull) continue;
      int a = parent_s[mi[e]], b = parent_s[mj[e]];
      if (a == b) continue;
      int m = a < b ? a : b, M = a < b ? b : a;
      int old = atomicMin(&parent_s[M], m);
      if (old > m) changed = 1;
    }
    __syncthreads();
    for (int rep = 0; rep < 3; ++rep) {
      for (int v = t; v < NN; v += 1024) parent_s[v] = parent_s[parent_s[v]];
      __syncthreads();
    }
    int ch = changed;
    __syncthreads();
    if (!ch) break;
  }
  for (int rep = 0; rep < 13; ++rep) {   // full compression -> parent_s[v] = comp min index
    for (int v = t; v < NN; v += 1024) parent_s[v] = parent_s[parent_s[v]];
    __syncthreads();
  }
  if (t == 0) rcnt = 0;
  __syncthreads();
  for (int v = t; v < NN; v += 1024)
    if (parent_s[v] == v) { int s = atomicAdd(&rcnt, 1); if (s < 16) roots[s] = v; }
  __syncthreads();
  if (t == 0) {                           // sort roots asc == first-occurrence label order
    int c = rcnt > 16 ? 16 : rcnt;
    for (int a = 1; a < c; ++a) {
      int x = roots[a]; int b2 = a - 1;
      while (b2 >= 0 && roots[b2] > x) { roots[b2 + 1] = roots[b2]; --b2; }
      roots[b2 + 1] = x;
    }
  }
  if (t < 8) szs[t] = 0;
  __syncthreads();
  if (t < rcnt && t < 16) rr[roots[t]] = t;
  __syncthreads();
  for (int v = t; v < NN; v += 1024) {
    int lab = rr[parent_s[v]];
    labels_g[v] = lab;
    atomicAdd(&szs[lab], 1);
  }
  __syncthreads();
  if (t < rcnt && t < 8) {
    float iv = 1.0f / sqrtf((float)szs[t] + 1e-10f);  // bit-matches reference P entries
    ivs[t] = iv; invs_g[t] = iv;
  }
  __syncthreads();
  for (int v = t; v < NN; v += 1024) {    // P at out+1572, row-major [4096][6]
    int lab = rr[parent_s[v]];
    float* base = out + 1572 + v * 6;
#pragma unroll
    for (int b2 = 0; b2 < 6; ++b2) base[b2] = (b2 == lab) ? ivs[lab] : 0.0f;
  }
}

// ===== coarse outputs, one kernel: blocks 0-63 X_coarse, 64-79 A_coarse =====
__global__ __launch_bounds__(256) void k_coarse(const float* __restrict__ X,
                                                const u64* __restrict__ bits,
                                                const int* __restrict__ labels,
                                                const float* __restrict__ invs,
                                                float* out) {
  int t = threadIdx.x;
  if (blockIdx.x < 64) {
    // ---- X_coarse = P^T X : label-indexed column sums ----
    __shared__ float acc[6][256];
    __shared__ int labs[64];
    __shared__ float ivl[64];
#pragma unroll
    for (int m = 0; m < 6; ++m) acc[m][t] = 0.0f;
    if (t < 64) { int v = blockIdx.x * 64 + t; int l = labels[v]; labs[t] = l; ivl[t] = invs[l]; }
    __syncthreads();
    int v0 = blockIdx.x * 64;
    for (int r = 0; r < 64; ++r) {
      float x = X[(size_t)(v0 + r) * 256 + t];
      acc[labs[r]][t] += ivl[r] * x;
    }
    __syncthreads();
#pragma unroll
    for (int m = 0; m < 6; ++m) atomicAdd(&out[m * 256 + t], acc[m][t]);
  } else {
    // ---- A_coarse = P^T A P : neighbor-label counts from bit rows ----
    __shared__ unsigned char labs8[NN];   // 4 KiB
    __shared__ float accA[36];
    __shared__ float ivsl[8];
    for (int v = t; v < NN; v += 256) labs8[v] = (unsigned char)labels[v];
    if (t < 36) accA[t] = 0.0f;
    if (t < 6) ivsl[t] = invs[t];
    __syncthreads();
    int i = (blockIdx.x - 64) * 256 + t;
    u64 cnt = 0;   // six 10-bit counters
    const u64* row = bits + (size_t)i * NCH;
    for (int c = 0; c < NCH; ++c) {
      u64 wm = row[c];
      while (wm) {
        int j = (c << 6) + __builtin_ctzll(wm);
        wm &= wm - 1;
        cnt += 1ull << (labs8[j] * 10);
      }
    }
    int li = labs8[i];
    float fi = ivsl[li];
#pragma unroll
    for (int b = 0; b < 6; ++b) {
      float cb = (float)((cnt >> (b * 10)) & 1023ull);
      if (cb != 0.0f) atomicAdd(&accA[li * 6 + b], fi * ivsl[b] * cb);
    }
    __syncthreads();
    if (t < 36) atomicAdd(&out[1536 + t], accA[t]);
  }
}

// ============================ launch ============================
extern "C" void kernel_launch(void* const* d_in, const int* in_sizes, int n_in,
                              void* d_out, int out_size, void* d_ws, size_t ws_size,
                              hipStream_t stream) {
  const float* X = (const float*)d_in[0];
  const float* A = (const float*)d_in[1];
  float* out = (float*)d_out;

  char* wp = (char*)d_ws;
  size_t off = 0;
#define WALLOC(ty, name, count) \
  ty* name = (ty*)(wp + off);   \
  off += (((size_t)(count) * sizeof(ty)) + 255) & ~(size_t)255;
  WALLOC(u64, bits, (size_t)NN * NCH)      // 2 MiB
  WALLOC(u16, inter, (size_t)NN * NN)      // 32 MiB
  WALLOC(u16, deg, NN)
  WALLOC(int, comp, NN)
  WALLOC(u64, nkey, NN)
  WALLOC(int, nu, NN)
  WALLOC(u64, mkey, 4352)
  WALLOC(int, mi, 4352)
  WALLOC(int, mj, 4352)
  WALLOC(int, labels, NN)
  WALLOC(float, invs, 8)
  WALLOC(int, ncomp, 1)
  WALLOC(int, mstcnt, 1)
#undef WALLOC
  if (off > ws_size) return;   // workspace too small: leave output zeroed (clean fail)

  k_packdeg<<<NN / 4, 256, 0, stream>>>(A, bits, deg, out, out_size, comp, ncomp, mstcnt);
  k_inter<<<2080, 256, 0, stream>>>(bits, inter);
  for (int ph = 0; ph < 12; ++ph) {
    k_scan<<<NN / 4, 256, 0, stream>>>(inter, deg, comp, ncomp, nkey, nu);
    k_merge<<<1, 1024, 0, stream>>>(nkey, nu, comp, ncomp, mstcnt, mkey, mi, mj,
                                    labels, invs, out);
  }
  k_coarse<<<80, 256, 0, stream>>>(X, bits, labels, invs, out);
}